// Round 5
// baseline (443.809 us; speedup 1.0000x reference)
//
#include <hip/hip_runtime.h>

#define Bsz 2
#define Lq  2048
#define Dm  1024
#define Hh  16

typedef __attribute__((ext_vector_type(8))) short bf16x8;
typedef __attribute__((ext_vector_type(4))) float f32x4;

#define MFMA16(a, b, c) __builtin_amdgcn_mfma_f32_16x16x32_bf16((a), (b), (c), 0, 0, 0)
#define EXP2F(x) __builtin_amdgcn_exp2f(x)

__device__ __forceinline__ short f2bf(float f) {
    union { float f; unsigned u; } v; v.f = f;
    unsigned r = v.u + 0x7fffu + ((v.u >> 16) & 1u);
    return (short)(r >> 16);
}

__device__ __forceinline__ float bf2f(unsigned short s) {
    union { float f; unsigned u; } t; t.u = ((unsigned)s) << 16;
    return t.f;
}

__device__ __forceinline__ int pk2(float a, float b) {
    union { float f; unsigned u; } ua, ub; ua.f = a; ub.f = b;
    return (int)((ua.u >> 16) | (ub.u & 0xffff0000u));
}

// async global->LDS, 16B per lane. LDS dest is wave-uniform base; HW appends lane*16.
__device__ __forceinline__ void gload16(const void* g, void* l) {
    __builtin_amdgcn_global_load_lds((const __attribute__((address_space(1))) void*)g,
                                     (__attribute__((address_space(3))) void*)l,
                                     16, 0, 0);
}

// ---------------- LayerNorm (fp32 in -> bf16 out) ----------------
__global__ __launch_bounds__(256) void ln_bf16(const float* __restrict__ x,
                                               const float* __restrict__ w,
                                               const float* __restrict__ b,
                                               short* __restrict__ out) {
    const int row = blockIdx.x;
    const int tid = threadIdx.x;
    const float4 v = ((const float4*)(x + (size_t)row * 1024))[tid];
    float s = v.x + v.y + v.z + v.w;
    float q = v.x * v.x + v.y * v.y + v.z * v.z + v.w * v.w;
    for (int off = 32; off > 0; off >>= 1) {
        s += __shfl_down(s, off);
        q += __shfl_down(q, off);
    }
    __shared__ float red[8];
    const int wave = tid >> 6;
    if ((tid & 63) == 0) { red[wave] = s; red[wave + 4] = q; }
    __syncthreads();
    s = red[0] + red[1] + red[2] + red[3];
    q = red[4] + red[5] + red[6] + red[7];
    const float mu = s * (1.0f / 1024.0f);
    const float var = q * (1.0f / 1024.0f) - mu * mu;
    const float rstd = rsqrtf(var + 1e-5f);
    const float4 wv = ((const float4*)w)[tid];
    const float4 bv = ((const float4*)b)[tid];
    short4 o;
    o.x = f2bf((v.x - mu) * rstd * wv.x + bv.x);
    o.y = f2bf((v.y - mu) * rstd * wv.y + bv.y);
    o.z = f2bf((v.z - mu) * rstd * wv.z + bv.z);
    o.w = f2bf((v.w - mu) * rstd * wv.w + bv.w);
    ((short4*)(out + (size_t)row * 1024))[tid] = o;
}

// ------ fused transpose+cvt for all 4 weights: W[K][N] -> Wt[N][K] (one launch) ------
__global__ __launch_bounds__(256) void tr_cvt_all(
    const float* __restrict__ attnw, const float* __restrict__ projw,
    const float* __restrict__ fc1w,  const float* __restrict__ fc2w,
    short* __restrict__ attnwT, short* __restrict__ projwT,
    short* __restrict__ fc1wT,  short* __restrict__ fc2wT) {
    int id = blockIdx.x;
    const float* W; short* Wt; int K, N, bx, by;
    if (id < 3072)      { W = attnw; Wt = attnwT; K = 1024; N = 3072; bx = id % 96;  by = id / 96; }
    else if (id < 4096) { id -= 3072; W = projw; Wt = projwT; K = 1024; N = 1024; bx = id & 31; by = id >> 5; }
    else if (id < 8192) { id -= 4096; W = fc1w;  Wt = fc1wT;  K = 1024; N = 4096; bx = id & 127; by = id >> 7; }
    else                { id -= 8192; W = fc2w;  Wt = fc2wT;  K = 4096; N = 1024; bx = id & 31; by = id >> 5; }
    __shared__ float t[32][33];
    const int n0 = bx * 32, k0 = by * 32;
    const int tx = threadIdx.x & 31, ty = threadIdx.x >> 5;  // ty 0..7
#pragma unroll
    for (int i = 0; i < 4; i++)
        t[ty + i * 8][tx] = W[(size_t)(k0 + ty + i * 8) * N + n0 + tx];
    __syncthreads();
#pragma unroll
    for (int i = 0; i < 4; i++)
        Wt[(size_t)(n0 + ty + i * 8) * K + k0 + tx] = f2bf(t[tx][ty + i * 8]);
}

// ---------------- GEMM (wide): C = A * Bt^T + bias, fused epilogues ----------------
// 128x128 tile, 4 waves, 4 blocks/CU cross-block latency hiding.
// Round-5: A-operand DIRECT FROM GLOBAL (flatmm-style). The MFMA A-frag pattern
// (lane=row l16, 16B at quad*8) is a natural per-lane global_load_dwordx4 from
// row-major A; issued before __syncthreads so the barrier's vmcnt(0) drain covers the
// latency. LDS stages B only (swizzled as round-4) -> ds_read count per block-step
// halves (64->32); MFMA becomes the binding pipe. A is L2-served (XCD swizzle keeps
// each row-band resident on one XCD's L2).
// EP 0: QKV split -> q[B][H][L][64], k[B][H][L][64], vt[B][H][64][L] (bf16)
// EP 2: outb = bf16(gelu_exact(C))
template <int EP>
__global__ __launch_bounds__(256, 4) void gemm_bt(
    const short* __restrict__ A, const short* __restrict__ Bt,
    const float* __restrict__ bias, int N, int K,
    short* __restrict__ qd, short* __restrict__ kd, short* __restrict__ vtd,
    short* __restrict__ outb) {
    __shared__ short Bs[128 * 64];
    const int tid = threadIdx.x;
    const int lane = tid & 63, w = tid >> 6;
    const int l16 = lane & 15, quad = lane >> 4;
    const int wr = (w & 1) * 64, wc = (w >> 1) * 64;
    const int n = blockIdx.x;
    const int row0 = ((n & 7) * 4 + ((n >> 3) & 3)) * 128;   // XCD owns 4 row-bands
    const int col0 = (n >> 5) * 128;                          // 4 same-XCD blocks share col
    const int srow = lane >> 3;                               // 0..7 within 8-row group
    const int scol = ((lane & 7) ^ srow) * 8;                 // pre-swizzled source slot

    f32x4 acc[4][4];
    const f32x4 z = {0.f, 0.f, 0.f, 0.f};
#pragma unroll
    for (int i = 0; i < 4; i++)
#pragma unroll
        for (int j = 0; j < 4; j++) acc[i][j] = z;

    const size_t brow = (size_t)(col0 + w * 32 + srow);
    const short* a0 = A + (size_t)(row0 + wr + l16) * K + quad * 8;  // per-lane A base

    for (int k0 = 0; k0 < K; k0 += 64) {
        // stage B (async DMA), then issue A vector loads; __syncthreads' vmcnt(0)
        // drain completes both before any consumption.
#pragma unroll
        for (int g = 0; g < 4; g++)
            gload16(Bt + (brow + g * 8) * K + k0 + scol, &Bs[(w * 32 + g * 8) * 64]);
        bf16x8 av[8];
#pragma unroll
        for (int kk = 0; kk < 2; kk++)
#pragma unroll
            for (int i = 0; i < 4; i++)
                av[kk * 4 + i] = *(const bf16x8*)(a0 + (size_t)(i * 16) * K + k0 + kk * 32);
        __syncthreads();
#pragma unroll
        for (int kk = 0; kk < 2; kk++) {
            const int rsl = ((kk * 4 + quad) ^ (l16 & 7)) * 8;
            bf16x8 bb[4];
#pragma unroll
            for (int j = 0; j < 4; j++) bb[j] = *(const bf16x8*)&Bs[(wc + j * 16 + l16) * 64 + rsl];
#pragma unroll
            for (int i = 0; i < 4; i++)
#pragma unroll
                for (int j = 0; j < 4; j++) acc[i][j] = MFMA16(av[kk * 4 + i], bb[j], acc[i][j]);
        }
        __syncthreads();
    }

    float bz[4];
#pragma unroll
    for (int j = 0; j < 4; j++) bz[j] = bias[col0 + wc + j * 16 + l16];

#pragma unroll
    for (int i = 0; i < 4; i++) {
#pragma unroll
        for (int r = 0; r < 4; r++) {
            const int grow = row0 + wr + i * 16 + quad * 4 + r;
#pragma unroll
            for (int j = 0; j < 4; j++) {
                const int gcol = col0 + wc + j * 16 + l16;
                const float v = acc[i][j][r] + bz[j];
                if constexpr (EP == 0) {
                    const int b = grow >> 11, l = grow & 2047;
                    const int sec = gcol >> 10, wi = gcol & 1023;
                    const int h = wi >> 6, d = wi & 63;
                    if (sec == 2) {
                        vtd[(((size_t)b * Hh + h) * 64 + d) * Lq + l] = f2bf(v);
                    } else {
                        short* dst = sec ? kd : qd;
                        dst[(((size_t)b * Hh + h) * Lq + l) * 64 + d] = f2bf(v);
                    }
                } else {
                    const float g = 0.5f * v * (1.0f + erff(v * 0.70710678118f));
                    outb[(size_t)grow * N + gcol] = f2bf(g);
                }
            }
        }
    }
}

// ------- split-K GEMM (N=1024): 1D grid of 256*S blocks, bf16 partials.
// Same A-direct + B-LDS package as gemm_bt; XCD swizzle as before.
__global__ __launch_bounds__(256, 4) void gemm_sk(
    const short* __restrict__ A, const short* __restrict__ Bt, int K, int zbits,
    short* __restrict__ Cp) {
    __shared__ short Bs[128 * 64];
    const int tid = threadIdx.x;
    const int lane = tid & 63, w = tid >> 6;
    const int l16 = lane & 15, quad = lane >> 4;
    const int wr = (w & 1) * 64, wc = (w >> 1) * 64;
    const int n = blockIdx.x;
    const int xcd = n & 7, t = n >> 3;
    const int col = t & 7, u = t >> 3;
    const int c = xcd * (4 << zbits) + u;          // (row,z) combo
    const int zsl = c & ((1 << zbits) - 1);
    const int row0 = (c >> zbits) * 128, col0 = col * 128;
    const int KS = K >> zbits;
    const int kbeg = zsl * KS, kend = kbeg + KS;
    const int srow = lane >> 3;
    const int scol = ((lane & 7) ^ srow) * 8;

    f32x4 acc[4][4];
    const f32x4 z = {0.f, 0.f, 0.f, 0.f};
#pragma unroll
    for (int i = 0; i < 4; i++)
#pragma unroll
        for (int j = 0; j < 4; j++) acc[i][j] = z;

    const size_t brow = (size_t)(col0 + w * 32 + srow);
    const short* a0 = A + (size_t)(row0 + wr + l16) * K + quad * 8;

    for (int k0 = kbeg; k0 < kend; k0 += 64) {
#pragma unroll
        for (int g = 0; g < 4; g++)
            gload16(Bt + (brow + g * 8) * K + k0 + scol, &Bs[(w * 32 + g * 8) * 64]);
        bf16x8 av[8];
#pragma unroll
        for (int kk = 0; kk < 2; kk++)
#pragma unroll
            for (int i = 0; i < 4; i++)
                av[kk * 4 + i] = *(const bf16x8*)(a0 + (size_t)(i * 16) * K + k0 + kk * 32);
        __syncthreads();
#pragma unroll
        for (int kk = 0; kk < 2; kk++) {
            const int rsl = ((kk * 4 + quad) ^ (l16 & 7)) * 8;
            bf16x8 bb[4];
#pragma unroll
            for (int j = 0; j < 4; j++) bb[j] = *(const bf16x8*)&Bs[(wc + j * 16 + l16) * 64 + rsl];
#pragma unroll
            for (int i = 0; i < 4; i++)
#pragma unroll
                for (int j = 0; j < 4; j++) acc[i][j] = MFMA16(av[kk * 4 + i], bb[j], acc[i][j]);
        }
        __syncthreads();
    }

    short* cp = Cp + (size_t)zsl * 4096 * 1024;
#pragma unroll
    for (int i = 0; i < 4; i++) {
#pragma unroll
        for (int r = 0; r < 4; r++) {
            const int grow = row0 + wr + i * 16 + quad * 4 + r;
#pragma unroll
            for (int j = 0; j < 4; j++) {
                const int gcol = col0 + wc + j * 16 + l16;
                cp[(size_t)grow * 1024 + gcol] = f2bf(acc[i][j][r]);
            }
        }
    }
}

// ------- split-K reduce: out[r][c] = res[r][c] + bias[c] + sum_s Cp[s][r][c] -------
__global__ __launch_bounds__(256) void sk_reduce(const short* __restrict__ Cp, int S,
                                                 const float* __restrict__ res,
                                                 const float* __restrict__ bias,
                                                 float* __restrict__ out) {
    const int row = blockIdx.x, tid = threadIdx.x;
    const size_t base = (size_t)row * 1024 + tid * 4;
    float4 a = ((const float4*)(res + (size_t)row * 1024))[tid];
    const float4 bz = ((const float4*)bias)[tid];
    a.x += bz.x; a.y += bz.y; a.z += bz.z; a.w += bz.w;
    for (int s = 0; s < S; s++) {
        const ushort4 c = *(const ushort4*)(Cp + (size_t)s * 4096 * 1024 + base);
        a.x += bf2f(c.x); a.y += bf2f(c.y); a.z += bf2f(c.z); a.w += bf2f(c.w);
    }
    *(float4*)(out + base) = a;
}

// ------- split-K reduce fused with LayerNorm: xout = res+bias+sum(Cp); hout = LN(xout) -------
__global__ __launch_bounds__(256) void sk_reduce_ln(const short* __restrict__ Cp, int S,
                                                    const float* __restrict__ res,
                                                    const float* __restrict__ bias,
                                                    const float* __restrict__ lnw,
                                                    const float* __restrict__ lnb,
                                                    float* __restrict__ xout,
                                                    short* __restrict__ hout) {
    const int row = blockIdx.x, tid = threadIdx.x;
    const size_t base = (size_t)row * 1024 + tid * 4;
    float4 a = ((const float4*)(res + (size_t)row * 1024))[tid];
    const float4 bz = ((const float4*)bias)[tid];
    a.x += bz.x; a.y += bz.y; a.z += bz.z; a.w += bz.w;
    for (int s = 0; s < S; s++) {
        const ushort4 c = *(const ushort4*)(Cp + (size_t)s * 4096 * 1024 + base);
        a.x += bf2f(c.x); a.y += bf2f(c.y); a.z += bf2f(c.z); a.w += bf2f(c.w);
    }
    *(float4*)(xout + base) = a;
    float sm = a.x + a.y + a.z + a.w;
    float qs = a.x * a.x + a.y * a.y + a.z * a.z + a.w * a.w;
    for (int off = 32; off > 0; off >>= 1) {
        sm += __shfl_down(sm, off);
        qs += __shfl_down(qs, off);
    }
    __shared__ float red[8];
    const int wave = tid >> 6;
    if ((tid & 63) == 0) { red[wave] = sm; red[wave + 4] = qs; }
    __syncthreads();
    sm = red[0] + red[1] + red[2] + red[3];
    qs = red[4] + red[5] + red[6] + red[7];
    const float mu = sm * (1.0f / 1024.0f);
    const float var = qs * (1.0f / 1024.0f) - mu * mu;
    const float rstd = rsqrtf(var + 1e-5f);
    const float4 wv = ((const float4*)lnw)[tid];
    const float4 bv = ((const float4*)lnb)[tid];
    short4 o;
    o.x = f2bf((a.x - mu) * rstd * wv.x + bv.x);
    o.y = f2bf((a.y - mu) * rstd * wv.y + bv.y);
    o.z = f2bf((a.z - mu) * rstd * wv.z + bv.z);
    o.w = f2bf((a.w - mu) * rstd * wv.w + bv.w);
    ((short4*)(hout + (size_t)row * 1024))[tid] = o;
}

// ---------------- causal flash attention (128-q blocks, dbuf staging, S^T/O^T) -------
// No-max softmax (scores bounded; shift-invariant), Q prescaled by c1, per-lane l
// partials reduced in epilogue. K-loop has zero cross-lane ops.
// Round-4 layout: 1D grid remap (head-per-XCD, complementary qblk pairing) + 128B-row
// XOR-swizzled K/V LDS (conflict-free b128 reads).
#define KP 72  // P row stride in shorts (144B, 16B-aligned)
__global__ __launch_bounds__(256, 2) void attn_kernel(const short* __restrict__ Q,
                                                      const short* __restrict__ Kb,
                                                      const short* __restrict__ Vt,
                                                      short* __restrict__ Y) {
    const int tid = threadIdx.x;
    const int lane = tid & 63, wave = tid >> 6;
    const int l16 = lane & 15, quad = lane >> 4;
    const int n = blockIdx.x;
    const int xcd = n & 7, m = n >> 3;             // m 0..63 within XCD
    const int bh = xcd * 4 + (m & 3);              // 4 heads per XCD
    const int mm = (m & 31) >> 2;                  // 0..7
    const int qblk = (m < 32) ? (15 - mm) : mm;    // first half heavy, second light
    const int qw = qblk * 128 + wave * 32;         // wave's first query

    const short* qg = Q + ((size_t)bh * Lq + qw) * 64;
    const short* kg = Kb + (size_t)bh * Lq * 64;
    const short* vg = Vt + (size_t)bh * 64 * Lq;

    __shared__ short sK[2][64 * 64];   // row = key, 64 dims (128B row), XOR-swizzled
    __shared__ short sV[2][64 * 64];   // row = dim, 64 keys (128B row), XOR-swizzled
    __shared__ short sP[4][32 * KP];
    short* wpP = sP[wave];

    const float c1 = 0.0450842213f;                // (1/32) * log2(e)

    // Q as B-operand frags, prescaled by c1 (folds the score scale into exp2 arg)
    bf16x8 qf[2][2];
#pragma unroll
    for (int c = 0; c < 2; c++)
#pragma unroll
        for (int d = 0; d < 2; d++) {
            bf16x8 v = *(const bf16x8*)(qg + (c * 16 + l16) * 64 + d * 32 + quad * 8);
            bf16x8 r;
#pragma unroll
            for (int i = 0; i < 8; i++) {
                union { float f; unsigned u; } t;
                t.u = ((unsigned)(unsigned short)v[i]) << 16;
                r[i] = f2bf(t.f * c1);
            }
            qf[c][d] = r;
        }

    f32x4 o[4][2];
    const f32x4 z = {0.f, 0.f, 0.f, 0.f};
#pragma unroll
    for (int j = 0; j < 4; j++)
#pragma unroll
        for (int c = 0; c < 2; c++) o[j][c] = z;
    float l_i[2] = {0.f, 0.f};                     // per-lane partial (16 keys/step)

    const int srow8 = lane >> 3;                   // 0..7 row within 8-row group
    const int sslot = ((lane & 7) ^ srow8) * 8;    // pre-swizzled source slot (shorts)
    const int r0 = wave * 16;                      // wave's 16-row staging band
    const int nst = 2 * qblk + 2;

    auto stage = [&](int s) {
        const int p = s & 1;
        const int kb = s * 64;
        gload16(kg + (size_t)(kb + r0 + srow8) * 64 + sslot,     &sK[p][r0 * 64]);
        gload16(kg + (size_t)(kb + r0 + 8 + srow8) * 64 + sslot, &sK[p][(r0 + 8) * 64]);
        gload16(vg + (size_t)(r0 + srow8) * Lq + kb + sslot,     &sV[p][r0 * 64]);
        gload16(vg + (size_t)(r0 + 8 + srow8) * Lq + kb + sslot, &sV[p][(r0 + 8) * 64]);
    };

    stage(0);

    for (int s = 0; s < nst; ++s) {
        const int p = s & 1;
        __syncthreads();                            // vmcnt(0) here completes stage(s)
        bf16x8 kf[4][2];
#pragma unroll
        for (int kt = 0; kt < 4; kt++)
#pragma unroll
            for (int d = 0; d < 2; d++)
                kf[kt][d] = *(const bf16x8*)&sK[p][(kt * 16 + l16) * 64 +
                                                   (((d * 4 + quad) ^ (l16 & 7)) * 8)];
        if (s + 1 < nst) stage(s + 1);

        // S^T = K * Q^T  (already scaled: exp2 arg directly)
        f32x4 st[4][2];
#pragma unroll
        for (int kt = 0; kt < 4; kt++)
#pragma unroll
            for (int c = 0; c < 2; c++) {
                st[kt][c] = MFMA16(kf[kt][0], qf[c][0], z);
                st[kt][c] = MFMA16(kf[kt][1], qf[c][1], st[kt][c]);
            }

        // causal mask (only near/past the diagonal of this wave's queries)
        const int rel = s * 64 - qblk * 128 - wave * 32;
        if (rel > -64) {
#pragma unroll
            for (int kt = 0; kt < 4; kt++)
#pragma unroll
                for (int c = 0; c < 2; c++)
#pragma unroll
                    for (int r = 0; r < 4; r++) {
                        const int krel = rel + kt * 16 + quad * 4 + r - c * 16;
                        if (krel > l16) st[kt][c][r] = -1e30f;
                    }
        }

        // no-max softmax numerators; P^T rows c*16+l16 via ds_write_b64
#pragma unroll
        for (int c = 0; c < 2; c++) {
            float pv[4][4], rs = 0.f;
#pragma unroll
            for (int kt = 0; kt < 4; kt++)
#pragma unroll
                for (int r = 0; r < 4; r++) {
                    pv[kt][r] = EXP2F(st[kt][c][r]);
                    rs += pv[kt][r];
                }
            l_i[c] += rs;
            short* wp = wpP + (c * 16 + l16) * KP;
#pragma unroll
            for (int kt = 0; kt < 4; kt++) {
                int2 pw; pw.x = pk2(pv[kt][0], pv[kt][1]); pw.y = pk2(pv[kt][2], pv[kt][3]);
                *(int2*)(wp + kt * 16 + quad * 4) = pw;
            }
        }

        // O^T += V^T * P^T
        bf16x8 pf[2][2];
#pragma unroll
        for (int c = 0; c < 2; c++) {
            pf[c][0] = *(const bf16x8*)(wpP + (c * 16 + l16) * KP + quad * 8);
            pf[c][1] = *(const bf16x8*)(wpP + (c * 16 + l16) * KP + 32 + quad * 8);
        }
#pragma unroll
        for (int j = 0; j < 4; j++) {
            const bf16x8 v0 = *(const bf16x8*)&sV[p][(j * 16 + l16) * 64 +
                                                     ((quad ^ (l16 & 7)) * 8)];
            const bf16x8 v1 = *(const bf16x8*)&sV[p][(j * 16 + l16) * 64 +
                                                     (((4 + quad) ^ (l16 & 7)) * 8)];
#pragma unroll
            for (int c = 0; c < 2; c++) {
                o[j][c] = MFMA16(v0, pf[c][0], o[j][c]);
                o[j][c] = MFMA16(v1, pf[c][1], o[j][c]);
            }
        }
    }

    // epilogue: reduce l across quads (deferred), O^T[dim][query] -> Y[b][q][h*64+dim]
    const int b = bh >> 4, h = bh & 15;
#pragma unroll
    for (int c = 0; c < 2; c++) {
        float ls = l_i[c];
        ls += __shfl_xor(ls, 16);
        ls += __shfl_xor(ls, 32);
        const float inv = 1.0f / ls;
        const size_t base = ((size_t)b * Lq + qw + c * 16 + l16) * 1024 + h * 64;
#pragma unroll
        for (int j = 0; j < 4; j++) {
            short4 s4;
            s4.x = f2bf(o[j][c][0] * inv);
            s4.y = f2bf(o[j][c][1] * inv);
            s4.z = f2bf(o[j][c][2] * inv);
            s4.w = f2bf(o[j][c][3] * inv);
            *(short4*)(Y + base + j * 16 + quad * 4) = s4;
        }
    }
}

extern "C" void kernel_launch(void* const* d_in, const int* in_sizes, int n_in,
                              void* d_out, int out_size, void* d_ws, size_t ws_size,
                              hipStream_t stream) {
    (void)in_sizes; (void)n_in; (void)out_size; (void)ws_size;
    const float* x     = (const float*)d_in[0];
    const float* ln1w  = (const float*)d_in[1];
    const float* ln1b  = (const float*)d_in[2];
    const float* ln2w  = (const float*)d_in[3];
    const float* ln2b  = (const float*)d_in[4];
    const float* attnw = (const float*)d_in[5];
    const float* attnb = (const float*)d_in[6];
    const float* projw = (const float*)d_in[7];
    const float* projb = (const float*)d_in[8];
    const float* fc1w  = (const float*)d_in[9];
    const float* fc1b  = (const float*)d_in[10];
    const float* fc2w  = (const float*)d_in[11];
    const float* fc2b  = (const float*)d_in[12];
    float* out = (float*)d_out;

    char* ws = (char*)d_ws;
    size_t off = 0;
    auto alloc = [&](size_t bytes) {
        void* p = ws + off;
        off += (bytes + 255) & ~(size_t)255;
        return p;
    };
    short* attnwT = (short*)alloc(3072ull * 1024 * 2);
    short* projwT = (short*)alloc(1024ull * 1024 * 2);
    short* fc1wT  = (short*)alloc(4096ull * 1024 * 2);
    short* fc2wT  = (short*)alloc(1024ull * 4096 * 2);
    short* hbuf   = (short*)alloc(4096ull * 1024 * 2);      // LN out (reused for LN2)
    short* qbuf   = (short*)alloc(4096ull * 1024 * 2);
    short* kbuf   = (short*)alloc(4096ull * 1024 * 2);
    short* vtbuf  = (short*)alloc(4096ull * 1024 * 2);
    short* ybuf   = (short*)alloc(4096ull * 1024 * 2);
    float* x1     = (float*)alloc(4096ull * 1024 * 4);
    short* Cp     = (short*)alloc(4ull * 4096 * 1024 * 2);  // split-K bf16 partials (32MB)
    short* hh = qbuf;  // q/k/vt/y are contiguous 32MB, dead after proj -> reuse for FC1 out

    // all weights -> bf16 transposed, one launch
    tr_cvt_all<<<12288, 256, 0, stream>>>(attnw, projw, fc1w, fc2w,
                                          attnwT, projwT, fc1wT, fc2wT);

    // attention branch
    ln_bf16<<<4096, 256, 0, stream>>>(x, ln1w, ln1b, hbuf);
    gemm_bt<0><<<768, 256, 0, stream>>>(hbuf, attnwT, attnb, 3072, 1024,
                                        qbuf, kbuf, vtbuf, nullptr);
    attn_kernel<<<512, 256, 0, stream>>>(qbuf, kbuf, vtbuf, ybuf);
    gemm_sk<<<512, 256, 0, stream>>>(ybuf, projwT, 1024, 1, Cp);
    // fused: x1 = x + projb + sum(Cp); hbuf = LN2(x1)
    sk_reduce_ln<<<4096, 256, 0, stream>>>(Cp, 2, x, projb, ln2w, ln2b, x1, hbuf);

    // MLP branch
    gemm_bt<2><<<1024, 256, 0, stream>>>(hbuf, fc1wT, fc1b, 4096, 1024,
                                         nullptr, nullptr, nullptr, hh);
    gemm_sk<<<1024, 256, 0, stream>>>(hh, fc2wT, 4096, 2, Cp);
    sk_reduce<<<4096, 256, 0, stream>>>(Cp, 4, x1, fc2b, out);
}

// Round 6
// 327.882 us; speedup vs baseline: 1.3536x; 1.3536x over previous
//
#include <hip/hip_runtime.h>

#define Bsz 2
#define Lq  2048
#define Dm  1024
#define Hh  16

typedef __attribute__((ext_vector_type(8))) short bf16x8;
typedef __attribute__((ext_vector_type(4))) float f32x4;

#define MFMA16(a, b, c) __builtin_amdgcn_mfma_f32_16x16x32_bf16((a), (b), (c), 0, 0, 0)
#define EXP2F(x) __builtin_amdgcn_exp2f(x)

__device__ __forceinline__ short f2bf(float f) {
    union { float f; unsigned u; } v; v.f = f;
    unsigned r = v.u + 0x7fffu + ((v.u >> 16) & 1u);
    return (short)(r >> 16);
}

__device__ __forceinline__ float bf2f(unsigned short s) {
    union { float f; unsigned u; } t; t.u = ((unsigned)s) << 16;
    return t.f;
}

__device__ __forceinline__ int pk2(float a, float b) {
    union { float f; unsigned u; } ua, ub; ua.f = a; ub.f = b;
    return (int)((ua.u >> 16) | (ub.u & 0xffff0000u));
}

// async global->LDS, 16B per lane. LDS dest is wave-uniform base; HW appends lane*16.
__device__ __forceinline__ void gload16(const void* g, void* l) {
    __builtin_amdgcn_global_load_lds((const __attribute__((address_space(1))) void*)g,
                                     (__attribute__((address_space(3))) void*)l,
                                     16, 0, 0);
}

// ---------------- LayerNorm (fp32 in -> bf16 out) ----------------
__global__ __launch_bounds__(256) void ln_bf16(const float* __restrict__ x,
                                               const float* __restrict__ w,
                                               const float* __restrict__ b,
                                               short* __restrict__ out) {
    const int row = blockIdx.x;
    const int tid = threadIdx.x;
    const float4 v = ((const float4*)(x + (size_t)row * 1024))[tid];
    float s = v.x + v.y + v.z + v.w;
    float q = v.x * v.x + v.y * v.y + v.z * v.z + v.w * v.w;
    for (int off = 32; off > 0; off >>= 1) {
        s += __shfl_down(s, off);
        q += __shfl_down(q, off);
    }
    __shared__ float red[8];
    const int wave = tid >> 6;
    if ((tid & 63) == 0) { red[wave] = s; red[wave + 4] = q; }
    __syncthreads();
    s = red[0] + red[1] + red[2] + red[3];
    q = red[4] + red[5] + red[6] + red[7];
    const float mu = s * (1.0f / 1024.0f);
    const float var = q * (1.0f / 1024.0f) - mu * mu;
    const float rstd = rsqrtf(var + 1e-5f);
    const float4 wv = ((const float4*)w)[tid];
    const float4 bv = ((const float4*)b)[tid];
    short4 o;
    o.x = f2bf((v.x - mu) * rstd * wv.x + bv.x);
    o.y = f2bf((v.y - mu) * rstd * wv.y + bv.y);
    o.z = f2bf((v.z - mu) * rstd * wv.z + bv.z);
    o.w = f2bf((v.w - mu) * rstd * wv.w + bv.w);
    ((short4*)(out + (size_t)row * 1024))[tid] = o;
}

// ------ fused transpose+cvt for all 4 weights: W[K][N] -> Wt[N][K] (one launch) ------
__global__ __launch_bounds__(256) void tr_cvt_all(
    const float* __restrict__ attnw, const float* __restrict__ projw,
    const float* __restrict__ fc1w,  const float* __restrict__ fc2w,
    short* __restrict__ attnwT, short* __restrict__ projwT,
    short* __restrict__ fc1wT,  short* __restrict__ fc2wT) {
    int id = blockIdx.x;
    const float* W; short* Wt; int K, N, bx, by;
    if (id < 3072)      { W = attnw; Wt = attnwT; K = 1024; N = 3072; bx = id % 96;  by = id / 96; }
    else if (id < 4096) { id -= 3072; W = projw; Wt = projwT; K = 1024; N = 1024; bx = id & 31; by = id >> 5; }
    else if (id < 8192) { id -= 4096; W = fc1w;  Wt = fc1wT;  K = 1024; N = 4096; bx = id & 127; by = id >> 7; }
    else                { id -= 8192; W = fc2w;  Wt = fc2wT;  K = 4096; N = 1024; bx = id & 31; by = id >> 5; }
    __shared__ float t[32][33];
    const int n0 = bx * 32, k0 = by * 32;
    const int tx = threadIdx.x & 31, ty = threadIdx.x >> 5;  // ty 0..7
#pragma unroll
    for (int i = 0; i < 4; i++)
        t[ty + i * 8][tx] = W[(size_t)(k0 + ty + i * 8) * N + n0 + tx];
    __syncthreads();
#pragma unroll
    for (int i = 0; i < 4; i++)
        Wt[(size_t)(n0 + ty + i * 8) * K + k0 + tx] = f2bf(t[tx][ty + i * 8]);
}

// ---------------- GEMM (wide): C = A * Bt^T + bias, fused epilogues ----------------
// Round-6: round-4 skeleton (128x128 tile, BK=64, row-XOR swizzle, conflict-free
// ds_read_b128) with single-barrier double-buffering. Four DISTINCT static LDS objects
// (As0/Bs0/As1/Bs1) + 2x-unrolled loop with compile-time buffer identity, so LLVM's
// waitcnt pass can prove compute(buf A) doesn't alias the in-flight DMA to buf B and
// won't insert a conservative vmcnt(0) before the frag reads. One __syncthreads per
// K-step (was 2); each stage's DMA latency is covered by its own block's compute phase
// before the draining barrier. LDS 64KB -> 2 blocks/CU.
// EP 0: QKV split -> q[B][H][L][64], k[B][H][L][64], vt[B][H][64][L] (bf16)
// EP 2: outb = bf16(gelu_exact(C))
template <int EP>
__global__ __launch_bounds__(256, 2) void gemm_bt(
    const short* __restrict__ A, const short* __restrict__ Bt,
    const float* __restrict__ bias, int N, int K,
    short* __restrict__ qd, short* __restrict__ kd, short* __restrict__ vtd,
    short* __restrict__ outb) {
    __shared__ short As0[128 * 64], Bs0[128 * 64];
    __shared__ short As1[128 * 64], Bs1[128 * 64];
    const int tid = threadIdx.x;
    const int lane = tid & 63, w = tid >> 6;
    const int l16 = lane & 15, quad = lane >> 4;
    const int wr = (w & 1) * 64, wc = (w >> 1) * 64;
    const int n = blockIdx.x;
    const int row0 = ((n & 7) * 4 + ((n >> 3) & 3)) * 128;   // XCD owns 4 row-bands
    const int col0 = (n >> 5) * 128;                          // 4 same-XCD blocks share col
    const int srow = lane >> 3;                               // 0..7 within 8-row group
    const int scol = ((lane & 7) ^ srow) * 8;                 // pre-swizzled source slot

    f32x4 acc[4][4];
    const f32x4 z = {0.f, 0.f, 0.f, 0.f};
#pragma unroll
    for (int i = 0; i < 4; i++)
#pragma unroll
        for (int j = 0; j < 4; j++) acc[i][j] = z;

    const size_t arow = (size_t)(row0 + w * 32 + srow);
    const size_t brow = (size_t)(col0 + w * 32 + srow);

    auto stage = [&](short* dA, short* dB, int t) {
        const int k0 = t << 6;
#pragma unroll
        for (int g = 0; g < 4; g++) {
            gload16(A + (arow + g * 8) * K + k0 + scol,  &dA[(w * 32 + g * 8) * 64]);
            gload16(Bt + (brow + g * 8) * K + k0 + scol, &dB[(w * 32 + g * 8) * 64]);
        }
    };
    auto compute = [&](const short* sA, const short* sB) {
#pragma unroll
        for (int kk = 0; kk < 2; kk++) {
            const int rsl = ((kk * 4 + quad) ^ (l16 & 7)) * 8;
            bf16x8 a[4], bb[4];
#pragma unroll
            for (int i = 0; i < 4; i++) a[i] = *(const bf16x8*)&sA[(wr + i * 16 + l16) * 64 + rsl];
#pragma unroll
            for (int j = 0; j < 4; j++) bb[j] = *(const bf16x8*)&sB[(wc + j * 16 + l16) * 64 + rsl];
#pragma unroll
            for (int i = 0; i < 4; i++)
#pragma unroll
                for (int j = 0; j < 4; j++) acc[i][j] = MFMA16(a[i], bb[j], acc[i][j]);
        }
    };

    const int NT = K >> 6;                         // 16 (K=1024) / 64 never odd here
    stage(As0, Bs0, 0);
    for (int t = 0; t < NT; t += 2) {
        __syncthreads();                           // buf0 ready (drains its DMA)
        if (t + 1 < NT) stage(As1, Bs1, t + 1);    // prefetch next into buf1
        compute(As0, Bs0);
        __syncthreads();                           // buf1 ready; buf0 readers done
        if (t + 2 < NT) stage(As0, Bs0, t + 2);    // prefetch into buf0
        compute(As1, Bs1);
    }

    float bz[4];
#pragma unroll
    for (int j = 0; j < 4; j++) bz[j] = bias[col0 + wc + j * 16 + l16];

#pragma unroll
    for (int i = 0; i < 4; i++) {
#pragma unroll
        for (int r = 0; r < 4; r++) {
            const int grow = row0 + wr + i * 16 + quad * 4 + r;
#pragma unroll
            for (int j = 0; j < 4; j++) {
                const int gcol = col0 + wc + j * 16 + l16;
                const float v = acc[i][j][r] + bz[j];
                if constexpr (EP == 0) {
                    const int b = grow >> 11, l = grow & 2047;
                    const int sec = gcol >> 10, wi = gcol & 1023;
                    const int h = wi >> 6, d = wi & 63;
                    if (sec == 2) {
                        vtd[(((size_t)b * Hh + h) * 64 + d) * Lq + l] = f2bf(v);
                    } else {
                        short* dst = sec ? kd : qd;
                        dst[(((size_t)b * Hh + h) * Lq + l) * 64 + d] = f2bf(v);
                    }
                } else {
                    const float g = 0.5f * v * (1.0f + erff(v * 0.70710678118f));
                    outb[(size_t)grow * N + gcol] = f2bf(g);
                }
            }
        }
    }
}

// ------- split-K GEMM (N=1024): 1D grid of 256*S blocks, bf16 partials.
// Same single-barrier dbuf package as gemm_bt; XCD swizzle as before.
__global__ __launch_bounds__(256, 2) void gemm_sk(
    const short* __restrict__ A, const short* __restrict__ Bt, int K, int zbits,
    short* __restrict__ Cp) {
    __shared__ short As0[128 * 64], Bs0[128 * 64];
    __shared__ short As1[128 * 64], Bs1[128 * 64];
    const int tid = threadIdx.x;
    const int lane = tid & 63, w = tid >> 6;
    const int l16 = lane & 15, quad = lane >> 4;
    const int wr = (w & 1) * 64, wc = (w >> 1) * 64;
    const int n = blockIdx.x;
    const int xcd = n & 7, t0 = n >> 3;
    const int col = t0 & 7, u = t0 >> 3;
    const int c = xcd * (4 << zbits) + u;          // (row,z) combo
    const int zsl = c & ((1 << zbits) - 1);
    const int row0 = (c >> zbits) * 128, col0 = col * 128;
    const int KS = K >> zbits;
    const int kbeg = zsl * KS;
    const int srow = lane >> 3;
    const int scol = ((lane & 7) ^ srow) * 8;

    f32x4 acc[4][4];
    const f32x4 z = {0.f, 0.f, 0.f, 0.f};
#pragma unroll
    for (int i = 0; i < 4; i++)
#pragma unroll
        for (int j = 0; j < 4; j++) acc[i][j] = z;

    const size_t arow = (size_t)(row0 + w * 32 + srow);
    const size_t brow = (size_t)(col0 + w * 32 + srow);

    auto stage = [&](short* dA, short* dB, int t) {
        const int k0 = kbeg + (t << 6);
#pragma unroll
        for (int g = 0; g < 4; g++) {
            gload16(A + (arow + g * 8) * K + k0 + scol,  &dA[(w * 32 + g * 8) * 64]);
            gload16(Bt + (brow + g * 8) * K + k0 + scol, &dB[(w * 32 + g * 8) * 64]);
        }
    };
    auto compute = [&](const short* sA, const short* sB) {
#pragma unroll
        for (int kk = 0; kk < 2; kk++) {
            const int rsl = ((kk * 4 + quad) ^ (l16 & 7)) * 8;
            bf16x8 a[4], bb[4];
#pragma unroll
            for (int i = 0; i < 4; i++) a[i] = *(const bf16x8*)&sA[(wr + i * 16 + l16) * 64 + rsl];
#pragma unroll
            for (int j = 0; j < 4; j++) bb[j] = *(const bf16x8*)&sB[(wc + j * 16 + l16) * 64 + rsl];
#pragma unroll
            for (int i = 0; i < 4; i++)
#pragma unroll
                for (int j = 0; j < 4; j++) acc[i][j] = MFMA16(a[i], bb[j], acc[i][j]);
        }
    };

    const int NT = KS >> 6;                        // 8 (proj) / 16 (FC2) -> even
    stage(As0, Bs0, 0);
    for (int t = 0; t < NT; t += 2) {
        __syncthreads();
        if (t + 1 < NT) stage(As1, Bs1, t + 1);
        compute(As0, Bs0);
        __syncthreads();
        if (t + 2 < NT) stage(As0, Bs0, t + 2);
        compute(As1, Bs1);
    }

    short* cp = Cp + (size_t)zsl * 4096 * 1024;
#pragma unroll
    for (int i = 0; i < 4; i++) {
#pragma unroll
        for (int r = 0; r < 4; r++) {
            const int grow = row0 + wr + i * 16 + quad * 4 + r;
#pragma unroll
            for (int j = 0; j < 4; j++) {
                const int gcol = col0 + wc + j * 16 + l16;
                cp[(size_t)grow * 1024 + gcol] = f2bf(acc[i][j][r]);
            }
        }
    }
}

// ------- split-K reduce: out[r][c] = res[r][c] + bias[c] + sum_s Cp[s][r][c] -------
__global__ __launch_bounds__(256) void sk_reduce(const short* __restrict__ Cp, int S,
                                                 const float* __restrict__ res,
                                                 const float* __restrict__ bias,
                                                 float* __restrict__ out) {
    const int row = blockIdx.x, tid = threadIdx.x;
    const size_t base = (size_t)row * 1024 + tid * 4;
    float4 a = ((const float4*)(res + (size_t)row * 1024))[tid];
    const float4 bz = ((const float4*)bias)[tid];
    a.x += bz.x; a.y += bz.y; a.z += bz.z; a.w += bz.w;
    for (int s = 0; s < S; s++) {
        const ushort4 c = *(const ushort4*)(Cp + (size_t)s * 4096 * 1024 + base);
        a.x += bf2f(c.x); a.y += bf2f(c.y); a.z += bf2f(c.z); a.w += bf2f(c.w);
    }
    *(float4*)(out + base) = a;
}

// ------- split-K reduce fused with LayerNorm: xout = res+bias+sum(Cp); hout = LN(xout) -------
__global__ __launch_bounds__(256) void sk_reduce_ln(const short* __restrict__ Cp, int S,
                                                    const float* __restrict__ res,
                                                    const float* __restrict__ bias,
                                                    const float* __restrict__ lnw,
                                                    const float* __restrict__ lnb,
                                                    float* __restrict__ xout,
                                                    short* __restrict__ hout) {
    const int row = blockIdx.x, tid = threadIdx.x;
    const size_t base = (size_t)row * 1024 + tid * 4;
    float4 a = ((const float4*)(res + (size_t)row * 1024))[tid];
    const float4 bz = ((const float4*)bias)[tid];
    a.x += bz.x; a.y += bz.y; a.z += bz.z; a.w += bz.w;
    for (int s = 0; s < S; s++) {
        const ushort4 c = *(const ushort4*)(Cp + (size_t)s * 4096 * 1024 + base);
        a.x += bf2f(c.x); a.y += bf2f(c.y); a.z += bf2f(c.z); a.w += bf2f(c.w);
    }
    *(float4*)(xout + base) = a;
    float sm = a.x + a.y + a.z + a.w;
    float qs = a.x * a.x + a.y * a.y + a.z * a.z + a.w * a.w;
    for (int off = 32; off > 0; off >>= 1) {
        sm += __shfl_down(sm, off);
        qs += __shfl_down(qs, off);
    }
    __shared__ float red[8];
    const int wave = tid >> 6;
    if ((tid & 63) == 0) { red[wave] = sm; red[wave + 4] = qs; }
    __syncthreads();
    sm = red[0] + red[1] + red[2] + red[3];
    qs = red[4] + red[5] + red[6] + red[7];
    const float mu = sm * (1.0f / 1024.0f);
    const float var = qs * (1.0f / 1024.0f) - mu * mu;
    const float rstd = rsqrtf(var + 1e-5f);
    const float4 wv = ((const float4*)lnw)[tid];
    const float4 bv = ((const float4*)lnb)[tid];
    short4 o;
    o.x = f2bf((a.x - mu) * rstd * wv.x + bv.x);
    o.y = f2bf((a.y - mu) * rstd * wv.y + bv.y);
    o.z = f2bf((a.z - mu) * rstd * wv.z + bv.z);
    o.w = f2bf((a.w - mu) * rstd * wv.w + bv.w);
    ((short4*)(hout + (size_t)row * 1024))[tid] = o;
}

// ---------------- causal flash attention (128-q blocks, dbuf staging, S^T/O^T) -------
// No-max softmax (scores bounded; shift-invariant), Q prescaled by c1, per-lane l
// partials reduced in epilogue. K-loop has zero cross-lane ops.
// Round-4 layout: 1D grid remap (head-per-XCD, complementary qblk pairing) + 128B-row
// XOR-swizzled K/V LDS (conflict-free b128 reads).
#define KP 72  // P row stride in shorts (144B, 16B-aligned)
__global__ __launch_bounds__(256, 2) void attn_kernel(const short* __restrict__ Q,
                                                      const short* __restrict__ Kb,
                                                      const short* __restrict__ Vt,
                                                      short* __restrict__ Y) {
    const int tid = threadIdx.x;
    const int lane = tid & 63, wave = tid >> 6;
    const int l16 = lane & 15, quad = lane >> 4;
    const int n = blockIdx.x;
    const int xcd = n & 7, m = n >> 3;             // m 0..63 within XCD
    const int bh = xcd * 4 + (m & 3);              // 4 heads per XCD
    const int mm = (m & 31) >> 2;                  // 0..7
    const int qblk = (m < 32) ? (15 - mm) : mm;    // first half heavy, second light
    const int qw = qblk * 128 + wave * 32;         // wave's first query

    const short* qg = Q + ((size_t)bh * Lq + qw) * 64;
    const short* kg = Kb + (size_t)bh * Lq * 64;
    const short* vg = Vt + (size_t)bh * 64 * Lq;

    __shared__ short sK[2][64 * 64];   // row = key, 64 dims (128B row), XOR-swizzled
    __shared__ short sV[2][64 * 64];   // row = dim, 64 keys (128B row), XOR-swizzled
    __shared__ short sP[4][32 * KP];
    short* wpP = sP[wave];

    const float c1 = 0.0450842213f;                // (1/32) * log2(e)

    // Q as B-operand frags, prescaled by c1 (folds the score scale into exp2 arg)
    bf16x8 qf[2][2];
#pragma unroll
    for (int c = 0; c < 2; c++)
#pragma unroll
        for (int d = 0; d < 2; d++) {
            bf16x8 v = *(const bf16x8*)(qg + (c * 16 + l16) * 64 + d * 32 + quad * 8);
            bf16x8 r;
#pragma unroll
            for (int i = 0; i < 8; i++) {
                union { float f; unsigned u; } t;
                t.u = ((unsigned)(unsigned short)v[i]) << 16;
                r[i] = f2bf(t.f * c1);
            }
            qf[c][d] = r;
        }

    f32x4 o[4][2];
    const f32x4 z = {0.f, 0.f, 0.f, 0.f};
#pragma unroll
    for (int j = 0; j < 4; j++)
#pragma unroll
        for (int c = 0; c < 2; c++) o[j][c] = z;
    float l_i[2] = {0.f, 0.f};                     // per-lane partial (16 keys/step)

    const int srow8 = lane >> 3;                   // 0..7 row within 8-row group
    const int sslot = ((lane & 7) ^ srow8) * 8;    // pre-swizzled source slot (shorts)
    const int r0 = wave * 16;                      // wave's 16-row staging band
    const int nst = 2 * qblk + 2;

    auto stage = [&](int s) {
        const int p = s & 1;
        const int kb = s * 64;
        gload16(kg + (size_t)(kb + r0 + srow8) * 64 + sslot,     &sK[p][r0 * 64]);
        gload16(kg + (size_t)(kb + r0 + 8 + srow8) * 64 + sslot, &sK[p][(r0 + 8) * 64]);
        gload16(vg + (size_t)(r0 + srow8) * Lq + kb + sslot,     &sV[p][r0 * 64]);
        gload16(vg + (size_t)(r0 + 8 + srow8) * Lq + kb + sslot, &sV[p][(r0 + 8) * 64]);
    };

    stage(0);

    for (int s = 0; s < nst; ++s) {
        const int p = s & 1;
        __syncthreads();                            // vmcnt(0) here completes stage(s)
        bf16x8 kf[4][2];
#pragma unroll
        for (int kt = 0; kt < 4; kt++)
#pragma unroll
            for (int d = 0; d < 2; d++)
                kf[kt][d] = *(const bf16x8*)&sK[p][(kt * 16 + l16) * 64 +
                                                   (((d * 4 + quad) ^ (l16 & 7)) * 8)];
        if (s + 1 < nst) stage(s + 1);

        // S^T = K * Q^T  (already scaled: exp2 arg directly)
        f32x4 st[4][2];
#pragma unroll
        for (int kt = 0; kt < 4; kt++)
#pragma unroll
            for (int c = 0; c < 2; c++) {
                st[kt][c] = MFMA16(kf[kt][0], qf[c][0], z);
                st[kt][c] = MFMA16(kf[kt][1], qf[c][1], st[kt][c]);
            }

        // causal mask (only near/past the diagonal of this wave's queries)
        const int rel = s * 64 - qblk * 128 - wave * 32;
        if (rel > -64) {
#pragma unroll
            for (int kt = 0; kt < 4; kt++)
#pragma unroll
                for (int c = 0; c < 2; c++)
#pragma unroll
                    for (int r = 0; r < 4; r++) {
                        const int krel = rel + kt * 16 + quad * 4 + r - c * 16;
                        if (krel > l16) st[kt][c][r] = -1e30f;
                    }
        }

        // no-max softmax numerators; P^T rows c*16+l16 via ds_write_b64
#pragma unroll
        for (int c = 0; c < 2; c++) {
            float pv[4][4], rs = 0.f;
#pragma unroll
            for (int kt = 0; kt < 4; kt++)
#pragma unroll
                for (int r = 0; r < 4; r++) {
                    pv[kt][r] = EXP2F(st[kt][c][r]);
                    rs += pv[kt][r];
                }
            l_i[c] += rs;
            short* wp = wpP + (c * 16 + l16) * KP;
#pragma unroll
            for (int kt = 0; kt < 4; kt++) {
                int2 pw; pw.x = pk2(pv[kt][0], pv[kt][1]); pw.y = pk2(pv[kt][2], pv[kt][3]);
                *(int2*)(wp + kt * 16 + quad * 4) = pw;
            }
        }

        // O^T += V^T * P^T
        bf16x8 pf[2][2];
#pragma unroll
        for (int c = 0; c < 2; c++) {
            pf[c][0] = *(const bf16x8*)(wpP + (c * 16 + l16) * KP + quad * 8);
            pf[c][1] = *(const bf16x8*)(wpP + (c * 16 + l16) * KP + 32 + quad * 8);
        }
#pragma unroll
        for (int j = 0; j < 4; j++) {
            const bf16x8 v0 = *(const bf16x8*)&sV[p][(j * 16 + l16) * 64 +
                                                     ((quad ^ (l16 & 7)) * 8)];
            const bf16x8 v1 = *(const bf16x8*)&sV[p][(j * 16 + l16) * 64 +
                                                     (((4 + quad) ^ (l16 & 7)) * 8)];
#pragma unroll
            for (int c = 0; c < 2; c++) {
                o[j][c] = MFMA16(v0, pf[c][0], o[j][c]);
                o[j][c] = MFMA16(v1, pf[c][1], o[j][c]);
            }
        }
    }

    // epilogue: reduce l across quads (deferred), O^T[dim][query] -> Y[b][q][h*64+dim]
    const int b = bh >> 4, h = bh & 15;
#pragma unroll
    for (int c = 0; c < 2; c++) {
        float ls = l_i[c];
        ls += __shfl_xor(ls, 16);
        ls += __shfl_xor(ls, 32);
        const float inv = 1.0f / ls;
        const size_t base = ((size_t)b * Lq + qw + c * 16 + l16) * 1024 + h * 64;
#pragma unroll
        for (int j = 0; j < 4; j++) {
            short4 s4;
            s4.x = f2bf(o[j][c][0] * inv);
            s4.y = f2bf(o[j][c][1] * inv);
            s4.z = f2bf(o[j][c][2] * inv);
            s4.w = f2bf(o[j][c][3] * inv);
            *(short4*)(Y + base + j * 16 + quad * 4) = s4;
        }
    }
}

extern "C" void kernel_launch(void* const* d_in, const int* in_sizes, int n_in,
                              void* d_out, int out_size, void* d_ws, size_t ws_size,
                              hipStream_t stream) {
    (void)in_sizes; (void)n_in; (void)out_size; (void)ws_size;
    const float* x     = (const float*)d_in[0];
    const float* ln1w  = (const float*)d_in[1];
    const float* ln1b  = (const float*)d_in[2];
    const float* ln2w  = (const float*)d_in[3];
    const float* ln2b  = (const float*)d_in[4];
    const float* attnw = (const float*)d_in[5];
    const float* attnb = (const float*)d_in[6];
    const float* projw = (const float*)d_in[7];
    const float* projb = (const float*)d_in[8];
    const float* fc1w  = (const float*)d_in[9];
    const float* fc1b  = (const float*)d_in[10];
    const float* fc2w  = (const float*)d_in[11];
    const float* fc2b  = (const float*)d_in[12];
    float* out = (float*)d_out;

    char* ws = (char*)d_ws;
    size_t off = 0;
    auto alloc = [&](size_t bytes) {
        void* p = ws + off;
        off += (bytes + 255) & ~(size_t)255;
        return p;
    };
    short* attnwT = (short*)alloc(3072ull * 1024 * 2);
    short* projwT = (short*)alloc(1024ull * 1024 * 2);
    short* fc1wT  = (short*)alloc(4096ull * 1024 * 2);
    short* fc2wT  = (short*)alloc(1024ull * 4096 * 2);
    short* hbuf   = (short*)alloc(4096ull * 1024 * 2);      // LN out (reused for LN2)
    short* qbuf   = (short*)alloc(4096ull * 1024 * 2);
    short* kbuf   = (short*)alloc(4096ull * 1024 * 2);
    short* vtbuf  = (short*)alloc(4096ull * 1024 * 2);
    short* ybuf   = (short*)alloc(4096ull * 1024 * 2);
    float* x1     = (float*)alloc(4096ull * 1024 * 4);
    short* Cp     = (short*)alloc(4ull * 4096 * 1024 * 2);  // split-K bf16 partials (32MB)
    short* hh = qbuf;  // q/k/vt/y are contiguous 32MB, dead after proj -> reuse for FC1 out

    // all weights -> bf16 transposed, one launch
    tr_cvt_all<<<12288, 256, 0, stream>>>(attnw, projw, fc1w, fc2w,
                                          attnwT, projwT, fc1wT, fc2wT);

    // attention branch
    ln_bf16<<<4096, 256, 0, stream>>>(x, ln1w, ln1b, hbuf);
    gemm_bt<0><<<768, 256, 0, stream>>>(hbuf, attnwT, attnb, 3072, 1024,
                                        qbuf, kbuf, vtbuf, nullptr);
    attn_kernel<<<512, 256, 0, stream>>>(qbuf, kbuf, vtbuf, ybuf);
    gemm_sk<<<512, 256, 0, stream>>>(ybuf, projwT, 1024, 1, Cp);
    // fused: x1 = x + projb + sum(Cp); hbuf = LN2(x1)
    sk_reduce_ln<<<4096, 256, 0, stream>>>(Cp, 2, x, projb, ln2w, ln2b, x1, hbuf);

    // MLP branch
    gemm_bt<2><<<1024, 256, 0, stream>>>(hbuf, fc1wT, fc1b, 4096, 1024,
                                         nullptr, nullptr, nullptr, hh);
    gemm_sk<<<1024, 256, 0, stream>>>(hh, fc2wT, 4096, 2, Cp);
    sk_reduce<<<4096, 256, 0, stream>>>(Cp, 4, x1, fc2b, out);
}

// Round 7
// 314.094 us; speedup vs baseline: 1.4130x; 1.0439x over previous
//
#include <hip/hip_runtime.h>

#define Bsz 2
#define Lq  2048
#define Dm  1024
#define Hh  16

typedef __attribute__((ext_vector_type(8))) short bf16x8;
typedef __attribute__((ext_vector_type(4))) float f32x4;

#define MFMA16(a, b, c) __builtin_amdgcn_mfma_f32_16x16x32_bf16((a), (b), (c), 0, 0, 0)
#define EXP2F(x) __builtin_amdgcn_exp2f(x)

__device__ __forceinline__ short f2bf(float f) {
    union { float f; unsigned u; } v; v.f = f;
    unsigned r = v.u + 0x7fffu + ((v.u >> 16) & 1u);
    return (short)(r >> 16);
}

__device__ __forceinline__ float bf2f(unsigned short s) {
    union { float f; unsigned u; } t; t.u = ((unsigned)s) << 16;
    return t.f;
}

__device__ __forceinline__ int pk2(float a, float b) {
    union { float f; unsigned u; } ua, ub; ua.f = a; ub.f = b;
    return (int)((ua.u >> 16) | (ub.u & 0xffff0000u));
}

// async global->LDS, 16B per lane. LDS dest is wave-uniform base; HW appends lane*16.
__device__ __forceinline__ void gload16(const void* g, void* l) {
    __builtin_amdgcn_global_load_lds((const __attribute__((address_space(1))) void*)g,
                                     (__attribute__((address_space(3))) void*)l,
                                     16, 0, 0);
}

// ------ fused prologue: weights W[K][N] -> Wt[N][K] bf16 (12288 blocks) + LN1 (4096) ------
__global__ __launch_bounds__(256) void prologue_all(
    const float* __restrict__ attnw, const float* __restrict__ projw,
    const float* __restrict__ fc1w,  const float* __restrict__ fc2w,
    short* __restrict__ attnwT, short* __restrict__ projwT,
    short* __restrict__ fc1wT,  short* __restrict__ fc2wT,
    const float* __restrict__ x, const float* __restrict__ lnw,
    const float* __restrict__ lnb, short* __restrict__ lnout) {
    int id = blockIdx.x;
    if (id >= 12288) {                 // ---- LayerNorm rows ----
        const int row = id - 12288;
        const int tid = threadIdx.x;
        const float4 v = ((const float4*)(x + (size_t)row * 1024))[tid];
        float s = v.x + v.y + v.z + v.w;
        float q = v.x * v.x + v.y * v.y + v.z * v.z + v.w * v.w;
        for (int off = 32; off > 0; off >>= 1) {
            s += __shfl_down(s, off);
            q += __shfl_down(q, off);
        }
        __shared__ float red[8];
        const int wave = tid >> 6;
        if ((tid & 63) == 0) { red[wave] = s; red[wave + 4] = q; }
        __syncthreads();
        s = red[0] + red[1] + red[2] + red[3];
        q = red[4] + red[5] + red[6] + red[7];
        const float mu = s * (1.0f / 1024.0f);
        const float var = q * (1.0f / 1024.0f) - mu * mu;
        const float rstd = rsqrtf(var + 1e-5f);
        const float4 wv = ((const float4*)lnw)[tid];
        const float4 bv = ((const float4*)lnb)[tid];
        short4 o;
        o.x = f2bf((v.x - mu) * rstd * wv.x + bv.x);
        o.y = f2bf((v.y - mu) * rstd * wv.y + bv.y);
        o.z = f2bf((v.z - mu) * rstd * wv.z + bv.z);
        o.w = f2bf((v.w - mu) * rstd * wv.w + bv.w);
        ((short4*)(lnout + (size_t)row * 1024))[tid] = o;
        return;
    }
    // ---- weight transpose+cvt ----
    const float* W; short* Wt; int K, N, bx, by;
    if (id < 3072)      { W = attnw; Wt = attnwT; K = 1024; N = 3072; bx = id % 96;  by = id / 96; }
    else if (id < 4096) { id -= 3072; W = projw; Wt = projwT; K = 1024; N = 1024; bx = id & 31; by = id >> 5; }
    else if (id < 8192) { id -= 4096; W = fc1w;  Wt = fc1wT;  K = 1024; N = 4096; bx = id & 127; by = id >> 7; }
    else                { id -= 8192; W = fc2w;  Wt = fc2wT;  K = 4096; N = 1024; bx = id & 31; by = id >> 5; }
    __shared__ float t[32][33];
    const int n0 = bx * 32, k0 = by * 32;
    const int tx = threadIdx.x & 31, ty = threadIdx.x >> 5;  // ty 0..7
#pragma unroll
    for (int i = 0; i < 4; i++)
        t[ty + i * 8][tx] = W[(size_t)(k0 + ty + i * 8) * N + n0 + tx];
    __syncthreads();
#pragma unroll
    for (int i = 0; i < 4; i++)
        Wt[(size_t)(n0 + ty + i * 8) * K + k0 + tx] = f2bf(t[tx][ty + i * 8]);
}

// ---------------- GEMM (wide): C = A * Bt^T + bias, fused epilogues ----------------
// Round-4 skeleton (proven 47.4us FC1): 128x128 tile, 4 waves, BK=64, row-XOR swizzle
// (conflict-free ds_read_b128), stage->sync->compute->sync, 4 blocks/CU cross-block
// latency hiding. Round-7: loop-invariant staging pointers (hoisted 64-bit addressing).
// EP 0: QKV split -> q[B][H][L][64], k[B][H][L][64], vt[B][H][64][L] (bf16)
// EP 2: outb = bf16(gelu_exact(C))
template <int EP>
__global__ __launch_bounds__(256, 4) void gemm_bt(
    const short* __restrict__ A, const short* __restrict__ Bt,
    const float* __restrict__ bias, int N, int K,
    short* __restrict__ qd, short* __restrict__ kd, short* __restrict__ vtd,
    short* __restrict__ outb) {
    __shared__ short As[128 * 64];
    __shared__ short Bs[128 * 64];
    const int tid = threadIdx.x;
    const int lane = tid & 63, w = tid >> 6;
    const int l16 = lane & 15, quad = lane >> 4;
    const int wr = (w & 1) * 64, wc = (w >> 1) * 64;
    const int n = blockIdx.x;
    const int row0 = ((n & 7) * 4 + ((n >> 3) & 3)) * 128;   // XCD owns 4 row-bands
    const int col0 = (n >> 5) * 128;                          // 4 same-XCD blocks share col
    const int srow = lane >> 3;                               // 0..7 within 8-row group
    const int scol = ((lane & 7) ^ srow) * 8;                 // pre-swizzled source slot

    f32x4 acc[4][4];
    const f32x4 z = {0.f, 0.f, 0.f, 0.f};
#pragma unroll
    for (int i = 0; i < 4; i++)
#pragma unroll
        for (int j = 0; j < 4; j++) acc[i][j] = z;

    // loop-invariant per-lane staging pointers (advance by 64 shorts per K-step)
    const short* pA[4];
    const short* pB[4];
#pragma unroll
    for (int g = 0; g < 4; g++) {
        pA[g] = A + (size_t)(row0 + w * 32 + g * 8 + srow) * K + scol;
        pB[g] = Bt + (size_t)(col0 + w * 32 + g * 8 + srow) * K + scol;
    }

    for (int k0 = 0; k0 < K; k0 += 64) {
#pragma unroll
        for (int g = 0; g < 4; g++) {
            gload16(pA[g], &As[(w * 32 + g * 8) * 64]);
            gload16(pB[g], &Bs[(w * 32 + g * 8) * 64]);
            pA[g] += 64; pB[g] += 64;
        }
        __syncthreads();
#pragma unroll
        for (int kk = 0; kk < 2; kk++) {
            const int rsl = ((kk * 4 + quad) ^ (l16 & 7)) * 8;
            bf16x8 a[4], bb[4];
#pragma unroll
            for (int i = 0; i < 4; i++) a[i] = *(const bf16x8*)&As[(wr + i * 16 + l16) * 64 + rsl];
#pragma unroll
            for (int j = 0; j < 4; j++) bb[j] = *(const bf16x8*)&Bs[(wc + j * 16 + l16) * 64 + rsl];
#pragma unroll
            for (int i = 0; i < 4; i++)
#pragma unroll
                for (int j = 0; j < 4; j++) acc[i][j] = MFMA16(a[i], bb[j], acc[i][j]);
        }
        __syncthreads();
    }

    float bz[4];
#pragma unroll
    for (int j = 0; j < 4; j++) bz[j] = bias[col0 + wc + j * 16 + l16];

#pragma unroll
    for (int i = 0; i < 4; i++) {
#pragma unroll
        for (int r = 0; r < 4; r++) {
            const int grow = row0 + wr + i * 16 + quad * 4 + r;
#pragma unroll
            for (int j = 0; j < 4; j++) {
                const int gcol = col0 + wc + j * 16 + l16;
                const float v = acc[i][j][r] + bz[j];
                if constexpr (EP == 0) {
                    const int b = grow >> 11, l = grow & 2047;
                    const int sec = gcol >> 10, wi = gcol & 1023;
                    const int h = wi >> 6, d = wi & 63;
                    if (sec == 2) {
                        vtd[(((size_t)b * Hh + h) * 64 + d) * Lq + l] = f2bf(v);
                    } else {
                        short* dst = sec ? kd : qd;
                        dst[(((size_t)b * Hh + h) * Lq + l) * 64 + d] = f2bf(v);
                    }
                } else {
                    const float g = 0.5f * v * (1.0f + erff(v * 0.70710678118f));
                    outb[(size_t)grow * N + gcol] = f2bf(g);
                }
            }
        }
    }
}

// ------- split-K GEMM (N=1024): 1D grid of 256*S blocks, bf16 partials.
// Same round-4 package as gemm_bt; XCD swizzle as before.
__global__ __launch_bounds__(256, 4) void gemm_sk(
    const short* __restrict__ A, const short* __restrict__ Bt, int K, int zbits,
    short* __restrict__ Cp) {
    __shared__ short As[128 * 64];
    __shared__ short Bs[128 * 64];
    const int tid = threadIdx.x;
    const int lane = tid & 63, w = tid >> 6;
    const int l16 = lane & 15, quad = lane >> 4;
    const int wr = (w & 1) * 64, wc = (w >> 1) * 64;
    const int n = blockIdx.x;
    const int xcd = n & 7, t = n >> 3;
    const int col = t & 7, u = t >> 3;
    const int c = xcd * (4 << zbits) + u;          // (row,z) combo
    const int zsl = c & ((1 << zbits) - 1);
    const int row0 = (c >> zbits) * 128, col0 = col * 128;
    const int KS = K >> zbits;
    const int kbeg = zsl * KS, kend = kbeg + KS;
    const int srow = lane >> 3;
    const int scol = ((lane & 7) ^ srow) * 8;

    f32x4 acc[4][4];
    const f32x4 z = {0.f, 0.f, 0.f, 0.f};
#pragma unroll
    for (int i = 0; i < 4; i++)
#pragma unroll
        for (int j = 0; j < 4; j++) acc[i][j] = z;

    const short* pA[4];
    const short* pB[4];
#pragma unroll
    for (int g = 0; g < 4; g++) {
        pA[g] = A + (size_t)(row0 + w * 32 + g * 8 + srow) * K + kbeg + scol;
        pB[g] = Bt + (size_t)(col0 + w * 32 + g * 8 + srow) * K + kbeg + scol;
    }

    for (int k0 = kbeg; k0 < kend; k0 += 64) {
#pragma unroll
        for (int g = 0; g < 4; g++) {
            gload16(pA[g], &As[(w * 32 + g * 8) * 64]);
            gload16(pB[g], &Bs[(w * 32 + g * 8) * 64]);
            pA[g] += 64; pB[g] += 64;
        }
        __syncthreads();
#pragma unroll
        for (int kk = 0; kk < 2; kk++) {
            const int rsl = ((kk * 4 + quad) ^ (l16 & 7)) * 8;
            bf16x8 a[4], bb[4];
#pragma unroll
            for (int i = 0; i < 4; i++) a[i] = *(const bf16x8*)&As[(wr + i * 16 + l16) * 64 + rsl];
#pragma unroll
            for (int j = 0; j < 4; j++) bb[j] = *(const bf16x8*)&Bs[(wc + j * 16 + l16) * 64 + rsl];
#pragma unroll
            for (int i = 0; i < 4; i++)
#pragma unroll
                for (int j = 0; j < 4; j++) acc[i][j] = MFMA16(a[i], bb[j], acc[i][j]);
        }
        __syncthreads();
    }

    short* cp = Cp + (size_t)zsl * 4096 * 1024;
#pragma unroll
    for (int i = 0; i < 4; i++) {
#pragma unroll
        for (int r = 0; r < 4; r++) {
            const int grow = row0 + wr + i * 16 + quad * 4 + r;
#pragma unroll
            for (int j = 0; j < 4; j++) {
                const int gcol = col0 + wc + j * 16 + l16;
                cp[(size_t)grow * 1024 + gcol] = f2bf(acc[i][j][r]);
            }
        }
    }
}

// ------- split-K reduce: out[r][c] = res[r][c] + bias[c] + sum_s Cp[s][r][c] -------
__global__ __launch_bounds__(256) void sk_reduce(const short* __restrict__ Cp, int S,
                                                 const float* __restrict__ res,
                                                 const float* __restrict__ bias,
                                                 float* __restrict__ out) {
    const int row = blockIdx.x, tid = threadIdx.x;
    const size_t base = (size_t)row * 1024 + tid * 4;
    float4 a = ((const float4*)(res + (size_t)row * 1024))[tid];
    const float4 bz = ((const float4*)bias)[tid];
    a.x += bz.x; a.y += bz.y; a.z += bz.z; a.w += bz.w;
    for (int s = 0; s < S; s++) {
        const ushort4 c = *(const ushort4*)(Cp + (size_t)s * 4096 * 1024 + base);
        a.x += bf2f(c.x); a.y += bf2f(c.y); a.z += bf2f(c.z); a.w += bf2f(c.w);
    }
    *(float4*)(out + base) = a;
}

// ------- split-K reduce fused with LayerNorm: xout = res+bias+sum(Cp); hout = LN(xout) -------
__global__ __launch_bounds__(256) void sk_reduce_ln(const short* __restrict__ Cp, int S,
                                                    const float* __restrict__ res,
                                                    const float* __restrict__ bias,
                                                    const float* __restrict__ lnw,
                                                    const float* __restrict__ lnb,
                                                    float* __restrict__ xout,
                                                    short* __restrict__ hout) {
    const int row = blockIdx.x, tid = threadIdx.x;
    const size_t base = (size_t)row * 1024 + tid * 4;
    float4 a = ((const float4*)(res + (size_t)row * 1024))[tid];
    const float4 bz = ((const float4*)bias)[tid];
    a.x += bz.x; a.y += bz.y; a.z += bz.z; a.w += bz.w;
    for (int s = 0; s < S; s++) {
        const ushort4 c = *(const ushort4*)(Cp + (size_t)s * 4096 * 1024 + base);
        a.x += bf2f(c.x); a.y += bf2f(c.y); a.z += bf2f(c.z); a.w += bf2f(c.w);
    }
    *(float4*)(xout + base) = a;
    float sm = a.x + a.y + a.z + a.w;
    float qs = a.x * a.x + a.y * a.y + a.z * a.z + a.w * a.w;
    for (int off = 32; off > 0; off >>= 1) {
        sm += __shfl_down(sm, off);
        qs += __shfl_down(qs, off);
    }
    __shared__ float red[8];
    const int wave = tid >> 6;
    if ((tid & 63) == 0) { red[wave] = sm; red[wave + 4] = qs; }
    __syncthreads();
    sm = red[0] + red[1] + red[2] + red[3];
    qs = red[4] + red[5] + red[6] + red[7];
    const float mu = sm * (1.0f / 1024.0f);
    const float var = qs * (1.0f / 1024.0f) - mu * mu;
    const float rstd = rsqrtf(var + 1e-5f);
    const float4 wv = ((const float4*)lnw)[tid];
    const float4 bv = ((const float4*)lnb)[tid];
    short4 o;
    o.x = f2bf((a.x - mu) * rstd * wv.x + bv.x);
    o.y = f2bf((a.y - mu) * rstd * wv.y + bv.y);
    o.z = f2bf((a.z - mu) * rstd * wv.z + bv.z);
    o.w = f2bf((a.w - mu) * rstd * wv.w + bv.w);
    ((short4*)(hout + (size_t)row * 1024))[tid] = o;
}

// ---------------- causal flash attention (128-q blocks, dbuf staging, S^T/O^T) -------
// No-max softmax (scores bounded; shift-invariant), Q prescaled by c1, per-lane l
// partials reduced in epilogue. K-loop has zero cross-lane ops.
// 1D grid remap (head-per-XCD, complementary qblk pairing) + 128B-row XOR-swizzled
// K/V LDS (conflict-free b128 reads).
#define KP 72  // P row stride in shorts (144B, 16B-aligned)
__global__ __launch_bounds__(256, 2) void attn_kernel(const short* __restrict__ Q,
                                                      const short* __restrict__ Kb,
                                                      const short* __restrict__ Vt,
                                                      short* __restrict__ Y) {
    const int tid = threadIdx.x;
    const int lane = tid & 63, wave = tid >> 6;
    const int l16 = lane & 15, quad = lane >> 4;
    const int n = blockIdx.x;
    const int xcd = n & 7, m = n >> 3;             // m 0..63 within XCD
    const int bh = xcd * 4 + (m & 3);              // 4 heads per XCD
    const int mm = (m & 31) >> 2;                  // 0..7
    const int qblk = (m < 32) ? (15 - mm) : mm;    // first half heavy, second light
    const int qw = qblk * 128 + wave * 32;         // wave's first query

    const short* qg = Q + ((size_t)bh * Lq + qw) * 64;
    const short* kg = Kb + (size_t)bh * Lq * 64;
    const short* vg = Vt + (size_t)bh * 64 * Lq;

    __shared__ short sK[2][64 * 64];   // row = key, 64 dims (128B row), XOR-swizzled
    __shared__ short sV[2][64 * 64];   // row = dim, 64 keys (128B row), XOR-swizzled
    __shared__ short sP[4][32 * KP];
    short* wpP = sP[wave];

    const float c1 = 0.0450842213f;                // (1/32) * log2(e)

    // Q as B-operand frags, prescaled by c1 (folds the score scale into exp2 arg)
    bf16x8 qf[2][2];
#pragma unroll
    for (int c = 0; c < 2; c++)
#pragma unroll
        for (int d = 0; d < 2; d++) {
            bf16x8 v = *(const bf16x8*)(qg + (c * 16 + l16) * 64 + d * 32 + quad * 8);
            bf16x8 r;
#pragma unroll
            for (int i = 0; i < 8; i++) {
                union { float f; unsigned u; } t;
                t.u = ((unsigned)(unsigned short)v[i]) << 16;
                r[i] = f2bf(t.f * c1);
            }
            qf[c][d] = r;
        }

    f32x4 o[4][2];
    const f32x4 z = {0.f, 0.f, 0.f, 0.f};
#pragma unroll
    for (int j = 0; j < 4; j++)
#pragma unroll
        for (int c = 0; c < 2; c++) o[j][c] = z;
    float l_i[2] = {0.f, 0.f};                     // per-lane partial (16 keys/step)

    const int srow8 = lane >> 3;                   // 0..7 row within 8-row group
    const int sslot = ((lane & 7) ^ srow8) * 8;    // pre-swizzled source slot (shorts)
    const int r0 = wave * 16;                      // wave's 16-row staging band
    const int nst = 2 * qblk + 2;

    auto stage = [&](int s) {
        const int p = s & 1;
        const int kb = s * 64;
        gload16(kg + (size_t)(kb + r0 + srow8) * 64 + sslot,     &sK[p][r0 * 64]);
        gload16(kg + (size_t)(kb + r0 + 8 + srow8) * 64 + sslot, &sK[p][(r0 + 8) * 64]);
        gload16(vg + (size_t)(r0 + srow8) * Lq + kb + sslot,     &sV[p][r0 * 64]);
        gload16(vg + (size_t)(r0 + 8 + srow8) * Lq + kb + sslot, &sV[p][(r0 + 8) * 64]);
    };

    stage(0);

    for (int s = 0; s < nst; ++s) {
        const int p = s & 1;
        __syncthreads();                            // vmcnt(0) here completes stage(s)
        bf16x8 kf[4][2];
#pragma unroll
        for (int kt = 0; kt < 4; kt++)
#pragma unroll
            for (int d = 0; d < 2; d++)
                kf[kt][d] = *(const bf16x8*)&sK[p][(kt * 16 + l16) * 64 +
                                                   (((d * 4 + quad) ^ (l16 & 7)) * 8)];
        if (s + 1 < nst) stage(s + 1);

        // S^T = K * Q^T  (already scaled: exp2 arg directly)
        f32x4 st[4][2];
#pragma unroll
        for (int kt = 0; kt < 4; kt++)
#pragma unroll
            for (int c = 0; c < 2; c++) {
                st[kt][c] = MFMA16(kf[kt][0], qf[c][0], z);
                st[kt][c] = MFMA16(kf[kt][1], qf[c][1], st[kt][c]);
            }

        // causal mask (only near/past the diagonal of this wave's queries)
        const int rel = s * 64 - qblk * 128 - wave * 32;
        if (rel > -64) {
#pragma unroll
            for (int kt = 0; kt < 4; kt++)
#pragma unroll
                for (int c = 0; c < 2; c++)
#pragma unroll
                    for (int r = 0; r < 4; r++) {
                        const int krel = rel + kt * 16 + quad * 4 + r - c * 16;
                        if (krel > l16) st[kt][c][r] = -1e30f;
                    }
        }

        // no-max softmax numerators; P^T rows c*16+l16 via ds_write_b64
#pragma unroll
        for (int c = 0; c < 2; c++) {
            float pv[4][4], rs = 0.f;
#pragma unroll
            for (int kt = 0; kt < 4; kt++)
#pragma unroll
                for (int r = 0; r < 4; r++) {
                    pv[kt][r] = EXP2F(st[kt][c][r]);
                    rs += pv[kt][r];
                }
            l_i[c] += rs;
            short* wp = wpP + (c * 16 + l16) * KP;
#pragma unroll
            for (int kt = 0; kt < 4; kt++) {
                int2 pw; pw.x = pk2(pv[kt][0], pv[kt][1]); pw.y = pk2(pv[kt][2], pv[kt][3]);
                *(int2*)(wp + kt * 16 + quad * 4) = pw;
            }
        }

        // O^T += V^T * P^T
        bf16x8 pf[2][2];
#pragma unroll
        for (int c = 0; c < 2; c++) {
            pf[c][0] = *(const bf16x8*)(wpP + (c * 16 + l16) * KP + quad * 8);
            pf[c][1] = *(const bf16x8*)(wpP + (c * 16 + l16) * KP + 32 + quad * 8);
        }
#pragma unroll
        for (int j = 0; j < 4; j++) {
            const bf16x8 v0 = *(const bf16x8*)&sV[p][(j * 16 + l16) * 64 +
                                                     ((quad ^ (l16 & 7)) * 8)];
            const bf16x8 v1 = *(const bf16x8*)&sV[p][(j * 16 + l16) * 64 +
                                                     (((4 + quad) ^ (l16 & 7)) * 8)];
#pragma unroll
            for (int c = 0; c < 2; c++) {
                o[j][c] = MFMA16(v0, pf[c][0], o[j][c]);
                o[j][c] = MFMA16(v1, pf[c][1], o[j][c]);
            }
        }
    }

    // epilogue: reduce l across quads (deferred), O^T[dim][query] -> Y[b][q][h*64+dim]
    const int b = bh >> 4, h = bh & 15;
#pragma unroll
    for (int c = 0; c < 2; c++) {
        float ls = l_i[c];
        ls += __shfl_xor(ls, 16);
        ls += __shfl_xor(ls, 32);
        const float inv = 1.0f / ls;
        const size_t base = ((size_t)b * Lq + qw + c * 16 + l16) * 1024 + h * 64;
#pragma unroll
        for (int j = 0; j < 4; j++) {
            short4 s4;
            s4.x = f2bf(o[j][c][0] * inv);
            s4.y = f2bf(o[j][c][1] * inv);
            s4.z = f2bf(o[j][c][2] * inv);
            s4.w = f2bf(o[j][c][3] * inv);
            *(short4*)(Y + base + j * 16 + quad * 4) = s4;
        }
    }
}

extern "C" void kernel_launch(void* const* d_in, const int* in_sizes, int n_in,
                              void* d_out, int out_size, void* d_ws, size_t ws_size,
                              hipStream_t stream) {
    (void)in_sizes; (void)n_in; (void)out_size; (void)ws_size;
    const float* x     = (const float*)d_in[0];
    const float* ln1w  = (const float*)d_in[1];
    const float* ln1b  = (const float*)d_in[2];
    const float* ln2w  = (const float*)d_in[3];
    const float* ln2b  = (const float*)d_in[4];
    const float* attnw = (const float*)d_in[5];
    const float* attnb = (const float*)d_in[6];
    const float* projw = (const float*)d_in[7];
    const float* projb = (const float*)d_in[8];
    const float* fc1w  = (const float*)d_in[9];
    const float* fc1b  = (const float*)d_in[10];
    const float* fc2w  = (const float*)d_in[11];
    const float* fc2b  = (const float*)d_in[12];
    float* out = (float*)d_out;

    char* ws = (char*)d_ws;
    size_t off = 0;
    auto alloc = [&](size_t bytes) {
        void* p = ws + off;
        off += (bytes + 255) & ~(size_t)255;
        return p;
    };
    short* attnwT = (short*)alloc(3072ull * 1024 * 2);
    short* projwT = (short*)alloc(1024ull * 1024 * 2);
    short* fc1wT  = (short*)alloc(4096ull * 1024 * 2);
    short* fc2wT  = (short*)alloc(1024ull * 4096 * 2);
    short* hbuf   = (short*)alloc(4096ull * 1024 * 2);      // LN out (reused for LN2)
    short* qbuf   = (short*)alloc(4096ull * 1024 * 2);
    short* kbuf   = (short*)alloc(4096ull * 1024 * 2);
    short* vtbuf  = (short*)alloc(4096ull * 1024 * 2);
    short* ybuf   = (short*)alloc(4096ull * 1024 * 2);
    float* x1     = (float*)alloc(4096ull * 1024 * 4);
    short* Cp     = (short*)alloc(4ull * 4096 * 1024 * 2);  // split-K bf16 partials (32MB)
    short* hh = qbuf;  // q/k/vt/y are contiguous 32MB, dead after proj -> reuse for FC1 out

    // weights -> bf16 transposed + LN1, one launch
    prologue_all<<<16384, 256, 0, stream>>>(attnw, projw, fc1w, fc2w,
                                            attnwT, projwT, fc1wT, fc2wT,
                                            x, ln1w, ln1b, hbuf);

    // attention branch
    gemm_bt<0><<<768, 256, 0, stream>>>(hbuf, attnwT, attnb, 3072, 1024,
                                        qbuf, kbuf, vtbuf, nullptr);
    attn_kernel<<<512, 256, 0, stream>>>(qbuf, kbuf, vtbuf, ybuf);
    gemm_sk<<<512, 256, 0, stream>>>(ybuf, projwT, 1024, 1, Cp);
    // fused: x1 = x + projb + sum(Cp); hbuf = LN2(x1)
    sk_reduce_ln<<<4096, 256, 0, stream>>>(Cp, 2, x, projb, ln2w, ln2b, x1, hbuf);

    // MLP branch
    gemm_bt<2><<<1024, 256, 0, stream>>>(hbuf, fc1wT, fc1b, 4096, 1024,
                                         nullptr, nullptr, nullptr, hh);
    gemm_sk<<<1024, 256, 0, stream>>>(hh, fc2wT, 4096, 2, Cp);
    sk_reduce<<<4096, 256, 0, stream>>>(Cp, 4, x1, fc2b, out);
}